// Round 12
// baseline (563.912 us; speedup 1.0000x reference)
//
#include <hip/hip_runtime.h>

typedef __bf16 bf16_t;
typedef __bf16 bf16x4 __attribute__((ext_vector_type(4)));
typedef __bf16 bf16x8 __attribute__((ext_vector_type(8)));
typedef float  f32x4  __attribute__((ext_vector_type(4)));
typedef unsigned u32x2 __attribute__((ext_vector_type(2)));

// flags[0] = floats-are-bf16, flags[1] = ints-are-64bit
__device__ inline float loadf(const void* p, size_t i, int bf) {
    return bf ? (float)((const bf16_t*)p)[i] : ((const float*)p)[i];
}
__device__ inline int eidx(const void* p, size_t i, int i64) {
    return i64 ? (int)((const long long*)p)[i] : ((const int*)p)[i];
}
__device__ inline float bflo(unsigned u) { return __uint_as_float(u << 16); }
__device__ inline float bfhi(unsigned u) { return __uint_as_float(u & 0xFFFF0000u); }

__device__ inline void gload16(const bf16_t* g, char* l) {
    __builtin_amdgcn_global_load_lds(
        (const __attribute__((address_space(1))) unsigned*)g,
        (__attribute__((address_space(3))) unsigned*)l, 16, 0, 0);
}

// ---------------- dtype detection (one wave, parallel) ----------------
__global__ void detect_k(const void* __restrict__ x, const void* __restrict__ ei,
                         int E, int* __restrict__ flags) {
    int l = threadIdx.x;
    const unsigned* xu = (const unsigned*)x;
    unsigned low = xu[l] & 0xFFFFu;
    unsigned ex = (low >> 7) & 0xFF;
    int cnt = __popcll(__ballot(ex >= 115 && ex <= 133));
    const unsigned* eu = (const unsigned*)ei;
    int lim = E < 64 ? E : 64;
    unsigned v = (l < lim) ? eu[2 * (size_t)l + 1] : 0u;
    unsigned long long nz = __ballot(v != 0u);
    if (l == 0) { flags[0] = (cnt >= 32) ? 1 : 0; flags[1] = (nz == 0ull) ? 1 : 0; }
}

// ---------------- x -> bf16 (copy or convert) ----------------
__global__ void tobf16_k(const void* __restrict__ in, bf16_t* __restrict__ out,
                         long n, const int* __restrict__ flags) {
    int bf = flags[0];
    long i = ((long)blockIdx.x * 256 + threadIdx.x) * 8;
    long stride = (long)gridDim.x * 256 * 8;
    if (bf) {
        for (; i < n; i += stride)
            *(bf16x8*)&out[i] = *(const bf16x8*)((const bf16_t*)in + i);
    } else {
        for (; i < n; i += stride) {
            f32x4 a = *(const f32x4*)((const float*)in + i);
            f32x4 b = *(const f32x4*)((const float*)in + i + 4);
            bf16x8 r;
            r[0]=(bf16_t)a[0]; r[1]=(bf16_t)a[1]; r[2]=(bf16_t)a[2]; r[3]=(bf16_t)a[3];
            r[4]=(bf16_t)b[0]; r[5]=(bf16_t)b[1]; r[6]=(bf16_t)b[2]; r[7]=(bf16_t)b[3];
            *(bf16x8*)&out[i] = r;
        }
    }
}

// ---------------- weight transpose+convert: out[C][R] = bf16(in[R][C]) ----------------
__global__ void transpose_k(const void* __restrict__ in, bf16_t* __restrict__ out,
                            int R, int C, const int* __restrict__ flags) {
    int bf = flags[0];
    int i = blockIdx.x * 256 + threadIdx.x;
    if (i < R * C) { int r = i / C, c = i % C; out[c * R + r] = (bf16_t)loadf(in, i, bf); }
}

// ---------------- bf16 MFMA GEMM: C[M,N] = A[M,K] @ BT[N,K]^T (PROVEN R7 form) ----------------
__global__ __launch_bounds__(256) void gemm128(const bf16_t* __restrict__ A,
                                               const bf16_t* __restrict__ BT,
                                               const void* __restrict__ bias,
                                               bf16_t* __restrict__ C,
                                               int M, int N, int K, int act,
                                               const int* __restrict__ flags,
                                               const void* __restrict__ a_srcp,
                                               const void* __restrict__ a_dstp,
                                               float* __restrict__ alsrc,
                                               float* __restrict__ aldst, int do_al) {
    int bf = flags[0];
    __shared__ __align__(16) char smem[34816];
    int t = threadIdx.x;
    int tm = blockIdx.x * 128;
    int tn = blockIdx.y * 128;
    int w = t >> 6, l = t & 63;
    int wr = (w >> 1) * 64, wc = (w & 1) * 64;
    int lr16 = l & 15, kg = l >> 4;
    int NK = K >> 5;

    f32x4 acc[4][4];
#pragma unroll
    for (int i = 0; i < 4; i++)
#pragma unroll
        for (int j = 0; j < 4; j++) acc[i][j] = (f32x4){0.f, 0.f, 0.f, 0.f};

    bool fast = (tm + 128 <= M);

    if (fast) {
        int buf = 0;
#pragma unroll
        for (int ii = 0; ii < 2; ii++) {
            int c = w + ii * 4;
            int rowa = tm + (c & 1) * 64 + l;
            int rowb = tn + (c & 1) * 64 + l;
            int kc = (c >> 1) * 8;
            gload16(A  + (size_t)rowa * K + kc, smem +         c * 1024 + l * 16);
            gload16(BT + (size_t)rowb * K + kc, smem + 16384 + c * 1024 + l * 16);
        }
        __syncthreads();
        for (int ks = 0; ks < NK; ks++) {
            if (ks + 1 < NK) {
                int k0 = (ks + 1) << 5;
                char* ab = smem + (buf ^ 1) * 8192;
                char* bb = smem + 16384 + (buf ^ 1) * 8192;
#pragma unroll
                for (int ii = 0; ii < 2; ii++) {
                    int c = w + ii * 4;
                    int rowa = tm + (c & 1) * 64 + l;
                    int rowb = tn + (c & 1) * 64 + l;
                    int kc = k0 + (c >> 1) * 8;
                    gload16(A  + (size_t)rowa * K + kc, ab + c * 1024 + l * 16);
                    gload16(BT + (size_t)rowb * K + kc, bb + c * 1024 + l * 16);
                }
            }
            const char* ab = smem + buf * 8192;
            const char* bb = smem + 16384 + buf * 8192;
            bf16x8 af[4], bg[4];
#pragma unroll
            for (int i = 0; i < 4; i++) {
                af[i] = *(const bf16x8*)(ab + ((size_t)(kg * 128 + wr + i * 16 + lr16)) * 16);
                bg[i] = *(const bf16x8*)(bb + ((size_t)(kg * 128 + wc + i * 16 + lr16)) * 16);
            }
#pragma unroll
            for (int i = 0; i < 4; i++)
#pragma unroll
                for (int j = 0; j < 4; j++)
                    acc[i][j] = __builtin_amdgcn_mfma_f32_16x16x32_bf16(af[i], bg[j], acc[i][j], 0, 0, 0);
            __syncthreads();
            buf ^= 1;
        }
    } else {
        int r = t >> 2, kg2 = t & 3;
        for (int ks = 0; ks < NK; ks++) {
            int k0 = ks << 5;
            bf16x8 va[2], vb[2];
#pragma unroll
            for (int j = 0; j < 2; j++) {
                int row = r + j * 64;
                int ra = tm + row; if (ra > M - 1) ra = M - 1;
                va[j] = *(const bf16x8*)(A + (size_t)ra * K + k0 + kg2 * 8);
                vb[j] = *(const bf16x8*)(BT + (size_t)(tn + row) * K + k0 + kg2 * 8);
            }
            __syncthreads();
#pragma unroll
            for (int j = 0; j < 2; j++) {
                int row = r + j * 64;
                *(bf16x8*)(smem + ((size_t)(kg2 * 128 + row)) * 16) = va[j];
                *(bf16x8*)(smem + 16384 + ((size_t)(kg2 * 128 + row)) * 16) = vb[j];
            }
            __syncthreads();
            bf16x8 af[4], bg[4];
#pragma unroll
            for (int i = 0; i < 4; i++) {
                af[i] = *(const bf16x8*)(smem + ((size_t)(kg * 128 + wr + i * 16 + lr16)) * 16);
                bg[i] = *(const bf16x8*)(smem + 16384 + ((size_t)(kg * 128 + wc + i * 16 + lr16)) * 16);
            }
#pragma unroll
            for (int i = 0; i < 4; i++)
#pragma unroll
                for (int j = 0; j < 4; j++)
                    acc[i][j] = __builtin_amdgcn_mfma_f32_16x16x32_bf16(af[i], bg[j], acc[i][j], 0, 0, 0);
        }
        __syncthreads();
    }

    int cr0 = kg * 4;

    if (do_al) {
        float asv[4], adv[4];
#pragma unroll
        for (int j = 0; j < 4; j++) {
            int col = tn + wc + j * 16 + lr16;
            asv[j] = loadf(a_srcp, col, bf);
            adv[j] = loadf(a_dstp, col, bf);
        }
        int head = (tn + wc) >> 6;
#pragma unroll
        for (int i = 0; i < 4; i++) {
#pragma unroll
            for (int q = 0; q < 4; q++) {
                float ps = acc[i][0][q]*asv[0] + acc[i][1][q]*asv[1] + acc[i][2][q]*asv[2] + acc[i][3][q]*asv[3];
                float pd = acc[i][0][q]*adv[0] + acc[i][1][q]*adv[1] + acc[i][2][q]*adv[2] + acc[i][3][q]*adv[3];
#pragma unroll
                for (int d = 1; d < 16; d <<= 1) { ps += __shfl_xor(ps, d); pd += __shfl_xor(pd, d); }
                int row = tm + wr + i * 16 + cr0 + q;
                if (lr16 == 0 && row < M) { alsrc[row * 4 + head] = ps; aldst[row * 4 + head] = pd; }
            }
        }
    }

    bf16_t (*Cst)[136] = (bf16_t(*)[136])smem;
#pragma unroll
    for (int i = 0; i < 4; i++) {
#pragma unroll
        for (int j = 0; j < 4; j++) {
            int col = wc + j * 16 + lr16;
            float bv = bias ? loadf(bias, tn + col, bf) : 0.f;
#pragma unroll
            for (int q = 0; q < 4; q++) {
                float v = acc[i][j][q] + bv;
                if (act) v = 0.5f * v * (1.f + erff(v * 0.70710678118f));
                Cst[wr + i * 16 + cr0 + q][col] = (bf16_t)v;
            }
        }
    }
    __syncthreads();
#pragma unroll
    for (int it = 0; it < 8; it++) {
        int idx = it * 256 + t;
        int row = idx >> 4;
        int c8 = (idx & 15) * 8;
        if (tm + row < M)
            *(bf16x8*)&C[(size_t)(tm + row) * N + tn + c8] = *(const bf16x8*)&Cst[row][c8];
    }
}

// ---------------- wide bf16 MFMA GEMM: 128x256 tile, same staging skeleton ----------------
// 2x MFMA per barrier-drain vs gemm128; for the FFN GEMMs (N multiple of 256).
__global__ __launch_bounds__(256) void gemm_wide(const bf16_t* __restrict__ A,
                                                 const bf16_t* __restrict__ BT,
                                                 const void* __restrict__ bias,
                                                 bf16_t* __restrict__ C,
                                                 int M, int N, int K, int act,
                                                 const int* __restrict__ flags) {
    int bf = flags[0];
    // A staging [2][4kg][128][16B] = 16KB at 0; B [2][4kg][256][16B] = 32KB at 16384.
    // Epilogue Cst[64][264] (33.8KB) overlays the staging region per 64-row pass.
    __shared__ __align__(16) char smem[49152];
    int t = threadIdx.x;
    int tm = blockIdx.x * 128;
    int tn = blockIdx.y * 256;
    int w = t >> 6, l = t & 63;
    int wr = (w >> 1) * 64, wc = (w & 1) * 128;
    int lr16 = l & 15, kg = l >> 4;
    int NK = K >> 5;

    f32x4 acc[4][8];
#pragma unroll
    for (int i = 0; i < 4; i++)
#pragma unroll
        for (int j = 0; j < 8; j++) acc[i][j] = (f32x4){0.f, 0.f, 0.f, 0.f};

    bool fast = (tm + 128 <= M);

    if (fast) {
        int buf = 0;
        // prologue: stage k-step 0 (A: set c=w+ii*4 like gemm128; B: wave w = row-block w, kg = ii)
#pragma unroll
        for (int ii = 0; ii < 2; ii++) {
            int c = w + ii * 4;
            int rowa = tm + (c & 1) * 64 + l;
            gload16(A + (size_t)rowa * K + (c >> 1) * 8, smem + c * 1024 + l * 16);
        }
#pragma unroll
        for (int ii = 0; ii < 4; ii++) {
            int rowb = tn + w * 64 + l;
            gload16(BT + (size_t)rowb * K + ii * 8, smem + 16384 + (w + ii * 4) * 1024 + l * 16);
        }
        __syncthreads();
        for (int ks = 0; ks < NK; ks++) {
            if (ks + 1 < NK) {
                int k0 = (ks + 1) << 5;
                char* ab = smem + (buf ^ 1) * 8192;
                char* bb = smem + 16384 + (buf ^ 1) * 16384;
#pragma unroll
                for (int ii = 0; ii < 2; ii++) {
                    int c = w + ii * 4;
                    int rowa = tm + (c & 1) * 64 + l;
                    gload16(A + (size_t)rowa * K + k0 + (c >> 1) * 8, ab + c * 1024 + l * 16);
                }
#pragma unroll
                for (int ii = 0; ii < 4; ii++) {
                    int rowb = tn + w * 64 + l;
                    gload16(BT + (size_t)rowb * K + k0 + ii * 8, bb + (w + ii * 4) * 1024 + l * 16);
                }
            }
            const char* ab = smem + buf * 8192;
            const char* bb = smem + 16384 + buf * 16384;
            bf16x8 af[4], bg[8];
#pragma unroll
            for (int i = 0; i < 4; i++)
                af[i] = *(const bf16x8*)(ab + (size_t)(kg * 2048 + (wr + i * 16 + lr16) * 16));
#pragma unroll
            for (int j = 0; j < 8; j++)
                bg[j] = *(const bf16x8*)(bb + (size_t)(kg * 4096 + (wc + j * 16 + lr16) * 16));
#pragma unroll
            for (int i = 0; i < 4; i++)
#pragma unroll
                for (int j = 0; j < 8; j++)
                    acc[i][j] = __builtin_amdgcn_mfma_f32_16x16x32_bf16(af[i], bg[j], acc[i][j], 0, 0, 0);
            __syncthreads();
            buf ^= 1;
        }
    } else {
        // M-edge slow path: clamped reg staging, 2 barriers/k-step, buf 0 only
        for (int ks = 0; ks < NK; ks++) {
            int k0 = ks << 5;
            bf16x8 va[2], vb[4];
#pragma unroll
            for (int ii = 0; ii < 2; ii++) {
                int c = w + ii * 4;
                int ra = tm + (c & 1) * 64 + l; if (ra > M - 1) ra = M - 1;
                va[ii] = *(const bf16x8*)(A + (size_t)ra * K + k0 + (c >> 1) * 8);
            }
#pragma unroll
            for (int ii = 0; ii < 4; ii++)
                vb[ii] = *(const bf16x8*)(BT + (size_t)(tn + w * 64 + l) * K + k0 + ii * 8);
            __syncthreads();
#pragma unroll
            for (int ii = 0; ii < 2; ii++)
                *(bf16x8*)(smem + (w + ii * 4) * 1024 + l * 16) = va[ii];
#pragma unroll
            for (int ii = 0; ii < 4; ii++)
                *(bf16x8*)(smem + 16384 + (w + ii * 4) * 1024 + l * 16) = vb[ii];
            __syncthreads();
            bf16x8 af[4], bg[8];
#pragma unroll
            for (int i = 0; i < 4; i++)
                af[i] = *(const bf16x8*)(smem + (size_t)(kg * 2048 + (wr + i * 16 + lr16) * 16));
#pragma unroll
            for (int j = 0; j < 8; j++)
                bg[j] = *(const bf16x8*)(smem + 16384 + (size_t)(kg * 4096 + (wc + j * 16 + lr16) * 16));
#pragma unroll
            for (int i = 0; i < 4; i++)
#pragma unroll
                for (int j = 0; j < 8; j++)
                    acc[i][j] = __builtin_amdgcn_mfma_f32_16x16x32_bf16(af[i], bg[j], acc[i][j], 0, 0, 0);
        }
        __syncthreads();
    }

    // ---- epilogue: two 64-row passes through Cst[64][264] -> coalesced stores
    bf16_t (*Cst)[264] = (bf16_t(*)[264])smem;
    int cr0 = kg * 4;
#pragma unroll
    for (int half = 0; half < 2; half++) {
        if ((w >> 1) == half) {
#pragma unroll
            for (int i = 0; i < 4; i++) {
#pragma unroll
                for (int j = 0; j < 8; j++) {
                    int col = wc + j * 16 + lr16;
                    float bv = bias ? loadf(bias, tn + col, bf) : 0.f;
#pragma unroll
                    for (int q = 0; q < 4; q++) {
                        float v = acc[i][j][q] + bv;
                        if (act) v = 0.5f * v * (1.f + erff(v * 0.70710678118f));
                        Cst[i * 16 + cr0 + q][col] = (bf16_t)v;
                    }
                }
            }
        }
        __syncthreads();
#pragma unroll
        for (int it = 0; it < 8; it++) {
            int idx = it * 256 + t;
            int row = idx >> 5;
            int c8 = (idx & 31) * 8;
            int gr = tm + half * 64 + row;
            if (gr < M)
                *(bf16x8*)&C[(size_t)gr * N + tn + c8] = *(const bf16x8*)&Cst[row][c8];
        }
        __syncthreads();
    }
}

// ---------------- CSR build ----------------
__global__ void deg_k(const void* __restrict__ ei, int* __restrict__ deg, int E, int N,
                      const int* __restrict__ flags) {
    int i64 = flags[1];
    int i = blockIdx.x * 256 + threadIdx.x;
    if (i < E) {
        int d = eidx(ei, (size_t)E + i, i64);
        if ((unsigned)d >= (unsigned)N) d = 0;
        atomicAdd(&deg[d], 1);
    }
}

__global__ __launch_bounds__(256) void scan1(const int* __restrict__ deg, int* __restrict__ offs,
                                             int* __restrict__ chunkSum) {
    __shared__ int s[256];
    int t = threadIdx.x, b = blockIdx.x;
    int v = deg[b * 256 + t];
    s[t] = v; __syncthreads();
#pragma unroll
    for (int d = 1; d < 256; d <<= 1) {
        int u = (t >= d) ? s[t - d] : 0;
        __syncthreads(); s[t] += u; __syncthreads();
    }
    offs[b * 256 + t] = s[t] - v;
    if (t == 255) chunkSum[b] = s[255];
}

__global__ __launch_bounds__(256) void scan2(const int* __restrict__ chunkSum, int* __restrict__ chunkOff, int nch) {
    __shared__ int s[256];
    int t = threadIdx.x;
    int v = (t < nch) ? chunkSum[t] : 0;
    s[t] = v; __syncthreads();
#pragma unroll
    for (int d = 1; d < 256; d <<= 1) {
        int u = (t >= d) ? s[t - d] : 0;
        __syncthreads(); s[t] += u; __syncthreads();
    }
    chunkOff[t] = s[t] - v;
}

__global__ void scan3(int* __restrict__ offs, const int* __restrict__ chunkOff,
                      int* __restrict__ cursor, int total) {
    int i = blockIdx.x * 256 + threadIdx.x;
    if (i < total) { int v = offs[i] + chunkOff[i >> 8]; offs[i] = v; cursor[i] = v; }
}

// scatter + per-edge softmax numerators (4 heads, bf16-packed) to CSR slot
__global__ void scatter_k(const void* __restrict__ ei, int* __restrict__ cursor,
                          int* __restrict__ csr, bf16_t* __restrict__ ewsb,
                          const float* __restrict__ alsrc, const float* __restrict__ aldst,
                          int E, int N, const int* __restrict__ flags) {
    int i64 = flags[1];
    int i = blockIdx.x * 256 + threadIdx.x;
    if (i < E) {
        int s = eidx(ei, i, i64);
        int d = eidx(ei, (size_t)E + i, i64);
        if ((unsigned)s >= (unsigned)N) s = 0;
        if ((unsigned)d >= (unsigned)N) d = 0;
        int p = atomicAdd(&cursor[d], 1);
        csr[p] = s;
        f32x4 as4 = *(const f32x4*)&alsrc[s * 4];
        f32x4 ad4 = *(const f32x4*)&aldst[d * 4];
        bf16x4 w4;
#pragma unroll
        for (int hh = 0; hh < 4; hh++) {
            float e = as4[hh] + ad4[hh];
            e = e > 0.f ? e : 0.2f * e;
            w4[hh] = (bf16_t)expf(fminf(e, 30.f));
        }
        *(bf16x4*)&ewsb[4 * (size_t)p] = w4;
    }
}

// ---------------- fused: aggregation + gat_b + residual + LN1 ----------------
// ONE WAVE PER NODE (4 nodes/block, zero barriers). Unroll-8 gather.
__global__ __launch_bounds__(256) void gat_agg_ln(
    const bf16_t* __restrict__ hbuf, const bf16_t* __restrict__ xb,
    const float* __restrict__ alsrc, const float* __restrict__ aldst,
    const int* __restrict__ offs, const int* __restrict__ csr,
    const bf16_t* __restrict__ ewsb,
    const void* __restrict__ gatb, const void* __restrict__ lng, const void* __restrict__ lnb,
    bf16_t* __restrict__ y, const int* __restrict__ flags, int N) {
    int bf = flags[0];
    int w = threadIdx.x >> 6, l = threadIdx.x & 63;
    int n = blockIdx.x * 4 + w;
    if (n >= N) return;
    int h = l >> 4;
    int col0 = l * 4;

    __shared__ int   srcs[4][64];
    __shared__ float ewt[4][4][68];

    int off = offs[n], deg = offs[n + 1] - off;

    float es = alsrc[n * 4 + h] + aldst[n * 4 + h];
    es = es > 0.f ? es : 0.2f * es;
    float wself = expf(fminf(es, 30.f));

    float a0 = 0.f, a1 = 0.f, a2 = 0.f, a3 = 0.f;
    f32x4 ssum = (f32x4){0.f, 0.f, 0.f, 0.f};

    for (int c0 = 0; c0 < deg; c0 += 64) {
        int cl = deg - c0; if (cl > 64) cl = 64;
        if (l < cl) {
            int sv = csr[off + c0 + l];
            srcs[w][l] = sv;
            bf16x4 wv4 = *(const bf16x4*)&ewsb[4 * (size_t)(off + c0 + l)];
            float w0 = (float)wv4[0], w1 = (float)wv4[1], w2 = (float)wv4[2], w3 = (float)wv4[3];
            ewt[w][0][l] = w0; ewt[w][1][l] = w1;
            ewt[w][2][l] = w2; ewt[w][3][l] = w3;
            ssum += (f32x4){w0, w1, w2, w3};
        }
        int i = 0;
        for (; i + 8 <= cl; i += 8) {
            int sv[8]; u32x2 vv[8];
#pragma unroll
            for (int k = 0; k < 8; k++) sv[k] = __builtin_amdgcn_readfirstlane(srcs[w][i + k]);
#pragma unroll
            for (int k = 0; k < 8; k++) vv[k] = ((const u32x2*)(hbuf + (size_t)sv[k] * 256))[l];
            f32x4 wqa = *(const f32x4*)&ewt[w][h][i];
            f32x4 wqb = *(const f32x4*)&ewt[w][h][i + 4];
#pragma unroll
            for (int k = 0; k < 4; k++) {
                a0 += wqa[k]*bflo(vv[k][0]); a1 += wqa[k]*bfhi(vv[k][0]);
                a2 += wqa[k]*bflo(vv[k][1]); a3 += wqa[k]*bfhi(vv[k][1]);
                a0 += wqb[k]*bflo(vv[k+4][0]); a1 += wqb[k]*bfhi(vv[k+4][0]);
                a2 += wqb[k]*bflo(vv[k+4][1]); a3 += wqb[k]*bfhi(vv[k+4][1]);
            }
        }
        for (; i + 4 <= cl; i += 4) {
            int s0 = __builtin_amdgcn_readfirstlane(srcs[w][i]);
            int s1 = __builtin_amdgcn_readfirstlane(srcs[w][i + 1]);
            int s2 = __builtin_amdgcn_readfirstlane(srcs[w][i + 2]);
            int s3 = __builtin_amdgcn_readfirstlane(srcs[w][i + 3]);
            u32x2 v0 = ((const u32x2*)(hbuf + (size_t)s0 * 256))[l];
            u32x2 v1 = ((const u32x2*)(hbuf + (size_t)s1 * 256))[l];
            u32x2 v2 = ((const u32x2*)(hbuf + (size_t)s2 * 256))[l];
            u32x2 v3 = ((const u32x2*)(hbuf + (size_t)s3 * 256))[l];
            f32x4 wq = *(const f32x4*)&ewt[w][h][i];
            a0 += wq[0]*bflo(v0[0]); a1 += wq[0]*bfhi(v0[0]); a2 += wq[0]*bflo(v0[1]); a3 += wq[0]*bfhi(v0[1]);
            a0 += wq[1]*bflo(v1[0]); a1 += wq[1]*bfhi(v1[0]); a2 += wq[1]*bflo(v1[1]); a3 += wq[1]*bfhi(v1[1]);
            a0 += wq[2]*bflo(v2[0]); a1 += wq[2]*bfhi(v2[0]); a2 += wq[2]*bflo(v2[1]); a3 += wq[2]*bfhi(v2[1]);
            a0 += wq[3]*bflo(v3[0]); a1 += wq[3]*bfhi(v3[0]); a2 += wq[3]*bflo(v3[1]); a3 += wq[3]*bfhi(v3[1]);
        }
        for (; i < cl; i++) {
            int sv = __builtin_amdgcn_readfirstlane(srcs[w][i]);
            float wgt = ewt[w][h][i];
            u32x2 v0 = ((const u32x2*)(hbuf + (size_t)sv * 256))[l];
            a0 += wgt*bflo(v0[0]); a1 += wgt*bfhi(v0[0]); a2 += wgt*bflo(v0[1]); a3 += wgt*bfhi(v0[1]);
        }
    }

#pragma unroll
    for (int d = 1; d < 64; d <<= 1) {
        ssum[0] += __shfl_xor(ssum[0], d);
        ssum[1] += __shfl_xor(ssum[1], d);
        ssum[2] += __shfl_xor(ssum[2], d);
        ssum[3] += __shfl_xor(ssum[3], d);
    }
    float dsum = (h == 0) ? ssum[0] : (h == 1) ? ssum[1] : (h == 2) ? ssum[2] : ssum[3];
    float di = 1.f / (dsum + wself);

    u32x2 sv2 = ((const u32x2*)(hbuf + (size_t)n * 256))[l];
    u32x2 xv  = ((const u32x2*)(xb   + (size_t)n * 256))[l];
    float v0f = (a0 + wself*bflo(sv2[0])) * di + loadf(gatb, col0 + 0, bf) + bflo(xv[0]);
    float v1f = (a1 + wself*bfhi(sv2[0])) * di + loadf(gatb, col0 + 1, bf) + bfhi(xv[0]);
    float v2f = (a2 + wself*bflo(sv2[1])) * di + loadf(gatb, col0 + 2, bf) + bflo(xv[1]);
    float v3f = (a3 + wself*bfhi(sv2[1])) * di + loadf(gatb, col0 + 3, bf) + bfhi(xv[1]);

    float s1 = v0f + v1f + v2f + v3f;
#pragma unroll
    for (int d = 1; d < 64; d <<= 1) s1 += __shfl_xor(s1, d);
    float mu = s1 * (1.f / 256.f);
    float c0f = v0f - mu, c1f = v1f - mu, c2f = v2f - mu, c3f = v3f - mu;
    float sq = c0f*c0f + c1f*c1f + c2f*c2f + c3f*c3f;
#pragma unroll
    for (int d = 1; d < 64; d <<= 1) sq += __shfl_xor(sq, d);
    float rs = rsqrtf(sq * (1.f / 256.f) + 1e-5f);

    bf16x4 o;
    o[0] = (bf16_t)(c0f * rs * loadf(lng, col0 + 0, bf) + loadf(lnb, col0 + 0, bf));
    o[1] = (bf16_t)(c1f * rs * loadf(lng, col0 + 1, bf) + loadf(lnb, col0 + 1, bf));
    o[2] = (bf16_t)(c2f * rs * loadf(lng, col0 + 2, bf) + loadf(lnb, col0 + 2, bf));
    o[3] = (bf16_t)(c3f * rs * loadf(lng, col0 + 3, bf) + loadf(lnb, col0 + 3, bf));
    *(bf16x4*)&y[(size_t)n * 256 + col0] = o;
}

// ---------------- final residual + LN2 (wave per row, vectorized) ----------------
__global__ __launch_bounds__(256) void ln_res(const bf16_t* __restrict__ f, const bf16_t* __restrict__ y,
                                              const void* __restrict__ g, const void* __restrict__ b,
                                              void* __restrict__ out, int N, const int* __restrict__ flags) {
    int bf = flags[0];
    int row = blockIdx.x * 4 + (threadIdx.x >> 6);
    int l = threadIdx.x & 63;
    if (row >= N) return;
    int col0 = l * 4;
    u32x2 fv = *(const u32x2*)(f + (size_t)row * 256 + col0);
    u32x2 yv = *(const u32x2*)(y + (size_t)row * 256 + col0);
    float v0 = bflo(fv[0]) + bflo(yv[0]);
    float v1 = bfhi(fv[0]) + bfhi(yv[0]);
    float v2 = bflo(fv[1]) + bflo(yv[1]);
    float v3 = bfhi(fv[1]) + bfhi(yv[1]);
    float s = v0 + v1 + v2 + v3;
#pragma unroll
    for (int d = 1; d < 64; d <<= 1) s += __shfl_xor(s, d);
    float mu = s * (1.f / 256.f);
    float c0 = v0 - mu, c1 = v1 - mu, c2 = v2 - mu, c3 = v3 - mu;
    float sq = c0*c0 + c1*c1 + c2*c2 + c3*c3;
#pragma unroll
    for (int d = 1; d < 64; d <<= 1) sq += __shfl_xor(sq, d);
    float rs = rsqrtf(sq * (1.f / 256.f) + 1e-5f);
    float o0 = c0 * rs * loadf(g, col0 + 0, bf) + loadf(b, col0 + 0, bf);
    float o1 = c1 * rs * loadf(g, col0 + 1, bf) + loadf(b, col0 + 1, bf);
    float o2 = c2 * rs * loadf(g, col0 + 2, bf) + loadf(b, col0 + 2, bf);
    float o3 = c3 * rs * loadf(g, col0 + 3, bf) + loadf(b, col0 + 3, bf);
    if (bf) {
        bf16x4 o; o[0]=(bf16_t)o0; o[1]=(bf16_t)o1; o[2]=(bf16_t)o2; o[3]=(bf16_t)o3;
        *(bf16x4*)&((bf16_t*)out)[(size_t)row * 256 + col0] = o;
    } else {
        f32x4 o = (f32x4){o0, o1, o2, o3};
        *(f32x4*)&((float*)out)[(size_t)row * 256 + col0] = o;
    }
}

extern "C" void kernel_launch(void* const* d_in, const int* in_sizes, int n_in,
                              void* d_out, int out_size, void* d_ws, size_t ws_size,
                              hipStream_t stream) {
    const void* x    = d_in[0];
    const void* ei   = d_in[1];
    const void* W    = d_in[2];
    const void* a_src= d_in[3];
    const void* a_dst= d_in[4];
    const void* gatb = d_in[5];
    const void* ln1g = d_in[6];
    const void* ln1b = d_in[7];
    const void* W1   = d_in[8];
    const void* b1   = d_in[9];
    const void* W2   = d_in[10];
    const void* b2   = d_in[11];
    const void* ln2g = d_in[12];
    const void* ln2b = d_in[13];

    const int DIM = 256, DFF = 512;
    int N = in_sizes[0] / DIM;   // 50000
    int E = in_sizes[1] / 2;     // 800000

    char* ws = (char*)d_ws;
    size_t o = 0;
    auto alloc = [&](size_t bytes) { void* p = ws + o; o += (bytes + 255) & ~(size_t)255; return p; };
    int*    flags  = (int*)alloc(256);
    bf16_t* WT     = (bf16_t*)alloc((size_t)DIM * DIM * 2);
    bf16_t* W1T    = (bf16_t*)alloc((size_t)DIM * DFF * 2);
    bf16_t* W2T    = (bf16_t*)alloc((size_t)DFF * DIM * 2);
    float*  alsrc  = (float*)alloc((size_t)N * 4 * 4);
    float*  aldst  = (float*)alloc((size_t)N * 4 * 4);
    int nch = (N + 255) / 256;
    int tot = nch * 256;
    int* deg      = (int*)alloc((size_t)tot * 4);
    int* offs     = (int*)alloc((size_t)(tot + 1) * 4);
    int* cursor   = (int*)alloc((size_t)tot * 4);
    int* chunkSum = (int*)alloc(256 * 4);
    int* chunkOff = (int*)alloc(256 * 4);
    int* csr      = (int*)alloc((size_t)E * 4);
    bf16_t* ewsb  = (bf16_t*)alloc((size_t)E * 8);
    bf16_t* h     = (bf16_t*)alloc((size_t)N * DIM * 2);
    bf16_t* yb    = (bf16_t*)alloc((size_t)N * DIM * 2);
    bf16_t* xb    = (bf16_t*)alloc((size_t)N * DIM * 2);
    bf16_t* fb    = h;   // h dead after gat_agg_ln; reuse for FFN output
    size_t remain = (ws_size > o) ? (ws_size - o) : 0;
    long CH = (long)(remain / ((size_t)DFF * 2));
    if (CH > N) CH = N;
    if (CH < 1024) CH = 1024;
    bf16_t* t1 = (bf16_t*)alloc((size_t)CH * DFF * 2);

    detect_k<<<1, 64, 0, stream>>>(x, ei, E, flags);
    hipMemsetAsync(deg, 0, (size_t)tot * 4, stream);

    tobf16_k<<<4096, 256, 0, stream>>>(x, xb, (long)N * DIM, flags);
    transpose_k<<<(DIM * DIM + 255) / 256, 256, 0, stream>>>(W,  WT,  DIM, DIM, flags);
    transpose_k<<<(DIM * DFF + 255) / 256, 256, 0, stream>>>(W1, W1T, DIM, DFF, flags);
    transpose_k<<<(DFF * DIM + 255) / 256, 256, 0, stream>>>(W2, W2T, DFF, DIM, flags);

    dim3 g1((N + 127) / 128, DIM / 128);
    gemm128<<<g1, 256, 0, stream>>>(xb, WT, nullptr, h, N, DIM, DIM, 0, flags,
                                    a_src, a_dst, alsrc, aldst, 1);

    deg_k<<<(E + 255) / 256, 256, 0, stream>>>(ei, deg, E, N, flags);
    scan1<<<nch, 256, 0, stream>>>(deg, offs, chunkSum);
    scan2<<<1, 256, 0, stream>>>(chunkSum, chunkOff, nch);
    scan3<<<(tot + 255) / 256, 256, 0, stream>>>(offs, chunkOff, cursor, tot);
    scatter_k<<<(E + 255) / 256, 256, 0, stream>>>(ei, cursor, csr, ewsb, alsrc, aldst, E, N, flags);

    gat_agg_ln<<<(N + 3) / 4, 256, 0, stream>>>(h, xb, alsrc, aldst, offs, csr, ewsb,
                                                gatb, ln1g, ln1b, yb, flags, N);

    for (long r0 = 0; r0 < N; r0 += CH) {
        int m = (int)((N - r0 < CH) ? (N - r0) : CH);
        dim3 g2((m + 127) / 128, DFF / 256);
        gemm_wide<<<g2, 256, 0, stream>>>(yb + r0 * DIM, W1T, b1, t1, m, DFF, DIM, 1, flags);
        dim3 g3((m + 127) / 128, DIM / 256);
        gemm_wide<<<g3, 256, 0, stream>>>(t1, W2T, b2, fb + r0 * DIM, m, DIM, DFF, 0, flags);
    }

    ln_res<<<(N + 3) / 4, 256, 0, stream>>>(fb, yb, ln2g, ln2b, d_out, N, flags);
}

// Round 13
// 362.565 us; speedup vs baseline: 1.5553x; 1.5553x over previous
//
#include <hip/hip_runtime.h>

typedef __bf16 bf16_t;
typedef __bf16 bf16x4 __attribute__((ext_vector_type(4)));
typedef __bf16 bf16x8 __attribute__((ext_vector_type(8)));
typedef float  f32x4  __attribute__((ext_vector_type(4)));
typedef unsigned u32x2 __attribute__((ext_vector_type(2)));

// flags[0] = floats-are-bf16, flags[1] = ints-are-64bit
__device__ inline float loadf(const void* p, size_t i, int bf) {
    return bf ? (float)((const bf16_t*)p)[i] : ((const float*)p)[i];
}
__device__ inline int eidx(const void* p, size_t i, int i64) {
    return i64 ? (int)((const long long*)p)[i] : ((const int*)p)[i];
}
__device__ inline float bflo(unsigned u) { return __uint_as_float(u << 16); }
__device__ inline float bfhi(unsigned u) { return __uint_as_float(u & 0xFFFF0000u); }

__device__ inline void gload16(const bf16_t* g, char* l) {
    __builtin_amdgcn_global_load_lds(
        (const __attribute__((address_space(1))) unsigned*)g,
        (__attribute__((address_space(3))) unsigned*)l, 16, 0, 0);
}

// ---------------- dtype detection (one wave, parallel) ----------------
__global__ void detect_k(const void* __restrict__ x, const void* __restrict__ ei,
                         int E, int* __restrict__ flags) {
    int l = threadIdx.x;
    const unsigned* xu = (const unsigned*)x;
    unsigned low = xu[l] & 0xFFFFu;
    unsigned ex = (low >> 7) & 0xFF;
    int cnt = __popcll(__ballot(ex >= 115 && ex <= 133));
    const unsigned* eu = (const unsigned*)ei;
    int lim = E < 64 ? E : 64;
    unsigned v = (l < lim) ? eu[2 * (size_t)l + 1] : 0u;
    unsigned long long nz = __ballot(v != 0u);
    if (l == 0) { flags[0] = (cnt >= 32) ? 1 : 0; flags[1] = (nz == 0ull) ? 1 : 0; }
}

// ---------------- x -> bf16 (convert only when input is f32) ----------------
__global__ void tobf16_k(const void* __restrict__ in, bf16_t* __restrict__ out,
                         long n, const int* __restrict__ flags) {
    if (flags[0]) return;   // bf16 input: consumers read x directly, skip copy
    long i = ((long)blockIdx.x * 256 + threadIdx.x) * 8;
    long stride = (long)gridDim.x * 256 * 8;
    for (; i < n; i += stride) {
        f32x4 a = *(const f32x4*)((const float*)in + i);
        f32x4 b = *(const f32x4*)((const float*)in + i + 4);
        bf16x8 r;
        r[0]=(bf16_t)a[0]; r[1]=(bf16_t)a[1]; r[2]=(bf16_t)a[2]; r[3]=(bf16_t)a[3];
        r[4]=(bf16_t)b[0]; r[5]=(bf16_t)b[1]; r[6]=(bf16_t)b[2]; r[7]=(bf16_t)b[3];
        *(bf16x8*)&out[i] = r;
    }
}

// ---------------- fused weight transpose+convert: WT / W1T / W2T in one launch ----------------
__global__ void transpose3_k(const void* __restrict__ W,  bf16_t* __restrict__ WT,
                             const void* __restrict__ W1, bf16_t* __restrict__ W1T,
                             const void* __restrict__ W2, bf16_t* __restrict__ W2T,
                             const int* __restrict__ flags) {
    int bf = flags[0];
    int i = blockIdx.x * 256 + threadIdx.x;
    if (i < 65536) {                       // W: 256x256
        int r = i >> 8, c = i & 255;
        WT[c * 256 + r] = (bf16_t)loadf(W, i, bf);
    } else if (i < 196608) {               // W1: 256x512
        int j = i - 65536;
        int r = j >> 9, c = j & 511;
        W1T[c * 256 + r] = (bf16_t)loadf(W1, j, bf);
    } else if (i < 327680) {               // W2: 512x256
        int j = i - 196608;
        int r = j >> 8, c = j & 255;
        W2T[c * 512 + r] = (bf16_t)loadf(W2, j, bf);
    }
}

// ---------------- bf16 MFMA GEMM: C[M,N] = A[M,K] @ BT[N,K]^T (PROVEN R7 form) ----------------
// a_raw: if non-null and input-is-bf16, use it as A directly (skips xb copy).
__global__ __launch_bounds__(256) void gemm128(const bf16_t* __restrict__ A_,
                                               const void* __restrict__ a_raw,
                                               const bf16_t* __restrict__ BT,
                                               const void* __restrict__ bias,
                                               bf16_t* __restrict__ C,
                                               int M, int N, int K, int act,
                                               const int* __restrict__ flags,
                                               const void* __restrict__ a_srcp,
                                               const void* __restrict__ a_dstp,
                                               float* __restrict__ alsrc,
                                               float* __restrict__ aldst, int do_al) {
    int bf = flags[0];
    const bf16_t* A = (a_raw && bf) ? (const bf16_t*)a_raw : A_;
    __shared__ __align__(16) char smem[34816];
    int t = threadIdx.x;
    int tm = blockIdx.x * 128;
    int tn = blockIdx.y * 128;
    int w = t >> 6, l = t & 63;
    int wr = (w >> 1) * 64, wc = (w & 1) * 64;
    int lr16 = l & 15, kg = l >> 4;
    int NK = K >> 5;

    f32x4 acc[4][4];
#pragma unroll
    for (int i = 0; i < 4; i++)
#pragma unroll
        for (int j = 0; j < 4; j++) acc[i][j] = (f32x4){0.f, 0.f, 0.f, 0.f};

    bool fast = (tm + 128 <= M);

    if (fast) {
        int buf = 0;
#pragma unroll
        for (int ii = 0; ii < 2; ii++) {
            int c = w + ii * 4;
            int rowa = tm + (c & 1) * 64 + l;
            int rowb = tn + (c & 1) * 64 + l;
            int kc = (c >> 1) * 8;
            gload16(A  + (size_t)rowa * K + kc, smem +         c * 1024 + l * 16);
            gload16(BT + (size_t)rowb * K + kc, smem + 16384 + c * 1024 + l * 16);
        }
        __syncthreads();
        for (int ks = 0; ks < NK; ks++) {
            if (ks + 1 < NK) {
                int k0 = (ks + 1) << 5;
                char* ab = smem + (buf ^ 1) * 8192;
                char* bb = smem + 16384 + (buf ^ 1) * 8192;
#pragma unroll
                for (int ii = 0; ii < 2; ii++) {
                    int c = w + ii * 4;
                    int rowa = tm + (c & 1) * 64 + l;
                    int rowb = tn + (c & 1) * 64 + l;
                    int kc = k0 + (c >> 1) * 8;
                    gload16(A  + (size_t)rowa * K + kc, ab + c * 1024 + l * 16);
                    gload16(BT + (size_t)rowb * K + kc, bb + c * 1024 + l * 16);
                }
            }
            const char* ab = smem + buf * 8192;
            const char* bb = smem + 16384 + buf * 8192;
            bf16x8 af[4], bg[4];
#pragma unroll
            for (int i = 0; i < 4; i++) {
                af[i] = *(const bf16x8*)(ab + ((size_t)(kg * 128 + wr + i * 16 + lr16)) * 16);
                bg[i] = *(const bf16x8*)(bb + ((size_t)(kg * 128 + wc + i * 16 + lr16)) * 16);
            }
#pragma unroll
            for (int i = 0; i < 4; i++)
#pragma unroll
                for (int j = 0; j < 4; j++)
                    acc[i][j] = __builtin_amdgcn_mfma_f32_16x16x32_bf16(af[i], bg[j], acc[i][j], 0, 0, 0);
            __syncthreads();
            buf ^= 1;
        }
    } else {
        int r = t >> 2, kg2 = t & 3;
        for (int ks = 0; ks < NK; ks++) {
            int k0 = ks << 5;
            bf16x8 va[2], vb[2];
#pragma unroll
            for (int j = 0; j < 2; j++) {
                int row = r + j * 64;
                int ra = tm + row; if (ra > M - 1) ra = M - 1;
                va[j] = *(const bf16x8*)(A + (size_t)ra * K + k0 + kg2 * 8);
                vb[j] = *(const bf16x8*)(BT + (size_t)(tn + row) * K + k0 + kg2 * 8);
            }
            __syncthreads();
#pragma unroll
            for (int j = 0; j < 2; j++) {
                int row = r + j * 64;
                *(bf16x8*)(smem + ((size_t)(kg2 * 128 + row)) * 16) = va[j];
                *(bf16x8*)(smem + 16384 + ((size_t)(kg2 * 128 + row)) * 16) = vb[j];
            }
            __syncthreads();
            bf16x8 af[4], bg[4];
#pragma unroll
            for (int i = 0; i < 4; i++) {
                af[i] = *(const bf16x8*)(smem + ((size_t)(kg * 128 + wr + i * 16 + lr16)) * 16);
                bg[i] = *(const bf16x8*)(smem + 16384 + ((size_t)(kg * 128 + wc + i * 16 + lr16)) * 16);
            }
#pragma unroll
            for (int i = 0; i < 4; i++)
#pragma unroll
                for (int j = 0; j < 4; j++)
                    acc[i][j] = __builtin_amdgcn_mfma_f32_16x16x32_bf16(af[i], bg[j], acc[i][j], 0, 0, 0);
        }
        __syncthreads();
    }

    int cr0 = kg * 4;

    if (do_al) {
        float asv[4], adv[4];
#pragma unroll
        for (int j = 0; j < 4; j++) {
            int col = tn + wc + j * 16 + lr16;
            asv[j] = loadf(a_srcp, col, bf);
            adv[j] = loadf(a_dstp, col, bf);
        }
        int head = (tn + wc) >> 6;
#pragma unroll
        for (int i = 0; i < 4; i++) {
#pragma unroll
            for (int q = 0; q < 4; q++) {
                float ps = acc[i][0][q]*asv[0] + acc[i][1][q]*asv[1] + acc[i][2][q]*asv[2] + acc[i][3][q]*asv[3];
                float pd = acc[i][0][q]*adv[0] + acc[i][1][q]*adv[1] + acc[i][2][q]*adv[2] + acc[i][3][q]*adv[3];
#pragma unroll
                for (int d = 1; d < 16; d <<= 1) { ps += __shfl_xor(ps, d); pd += __shfl_xor(pd, d); }
                int row = tm + wr + i * 16 + cr0 + q;
                if (lr16 == 0 && row < M) { alsrc[row * 4 + head] = ps; aldst[row * 4 + head] = pd; }
            }
        }
    }

    bf16_t (*Cst)[136] = (bf16_t(*)[136])smem;
#pragma unroll
    for (int i = 0; i < 4; i++) {
#pragma unroll
        for (int j = 0; j < 4; j++) {
            int col = wc + j * 16 + lr16;
            float bv = bias ? loadf(bias, tn + col, bf) : 0.f;
#pragma unroll
            for (int q = 0; q < 4; q++) {
                float v = acc[i][j][q] + bv;
                if (act) v = 0.5f * v * (1.f + erff(v * 0.70710678118f));
                Cst[wr + i * 16 + cr0 + q][col] = (bf16_t)v;
            }
        }
    }
    __syncthreads();
#pragma unroll
    for (int it = 0; it < 8; it++) {
        int idx = it * 256 + t;
        int row = idx >> 4;
        int c8 = (idx & 15) * 8;
        if (tm + row < M)
            *(bf16x8*)&C[(size_t)(tm + row) * N + tn + c8] = *(const bf16x8*)&Cst[row][c8];
    }
}

// ---------------- CSR build ----------------
__global__ void deg_k(const void* __restrict__ ei, int* __restrict__ deg, int E, int N,
                      const int* __restrict__ flags) {
    int i64 = flags[1];
    int i = blockIdx.x * 256 + threadIdx.x;
    if (i < E) {
        int d = eidx(ei, (size_t)E + i, i64);
        if ((unsigned)d >= (unsigned)N) d = 0;
        atomicAdd(&deg[d], 1);
    }
}

__global__ __launch_bounds__(256) void scan1(const int* __restrict__ deg, int* __restrict__ offs,
                                             int* __restrict__ chunkSum) {
    __shared__ int s[256];
    int t = threadIdx.x, b = blockIdx.x;
    int v = deg[b * 256 + t];
    s[t] = v; __syncthreads();
#pragma unroll
    for (int d = 1; d < 256; d <<= 1) {
        int u = (t >= d) ? s[t - d] : 0;
        __syncthreads(); s[t] += u; __syncthreads();
    }
    offs[b * 256 + t] = s[t] - v;
    if (t == 255) chunkSum[b] = s[255];
}

__global__ __launch_bounds__(256) void scan2(const int* __restrict__ chunkSum, int* __restrict__ chunkOff, int nch) {
    __shared__ int s[256];
    int t = threadIdx.x;
    int v = (t < nch) ? chunkSum[t] : 0;
    s[t] = v; __syncthreads();
#pragma unroll
    for (int d = 1; d < 256; d <<= 1) {
        int u = (t >= d) ? s[t - d] : 0;
        __syncthreads(); s[t] += u; __syncthreads();
    }
    chunkOff[t] = s[t] - v;
}

__global__ void scan3(int* __restrict__ offs, const int* __restrict__ chunkOff,
                      int* __restrict__ cursor, int total) {
    int i = blockIdx.x * 256 + threadIdx.x;
    if (i < total) { int v = offs[i] + chunkOff[i >> 8]; offs[i] = v; cursor[i] = v; }
}

// scatter + per-edge softmax numerators (4 heads, bf16-packed) to CSR slot
__global__ void scatter_k(const void* __restrict__ ei, int* __restrict__ cursor,
                          int* __restrict__ csr, bf16_t* __restrict__ ewsb,
                          const float* __restrict__ alsrc, const float* __restrict__ aldst,
                          int E, int N, const int* __restrict__ flags) {
    int i64 = flags[1];
    int i = blockIdx.x * 256 + threadIdx.x;
    if (i < E) {
        int s = eidx(ei, i, i64);
        int d = eidx(ei, (size_t)E + i, i64);
        if ((unsigned)s >= (unsigned)N) s = 0;
        if ((unsigned)d >= (unsigned)N) d = 0;
        int p = atomicAdd(&cursor[d], 1);
        csr[p] = s;
        f32x4 as4 = *(const f32x4*)&alsrc[s * 4];
        f32x4 ad4 = *(const f32x4*)&aldst[d * 4];
        bf16x4 w4;
#pragma unroll
        for (int hh = 0; hh < 4; hh++) {
            float e = as4[hh] + ad4[hh];
            e = e > 0.f ? e : 0.2f * e;
            w4[hh] = (bf16_t)expf(fminf(e, 30.f));
        }
        *(bf16x4*)&ewsb[4 * (size_t)p] = w4;
    }
}

// ---------------- fused: aggregation + gat_b + residual + LN1 ----------------
// ONE WAVE PER NODE (4 nodes/block, zero barriers). Unroll-8 gather.
// Residual: bf16 x directly when input is bf16, else converted xb.
__global__ __launch_bounds__(256) void gat_agg_ln(
    const bf16_t* __restrict__ hbuf, const bf16_t* __restrict__ xb_,
    const void* __restrict__ x_raw,
    const float* __restrict__ alsrc, const float* __restrict__ aldst,
    const int* __restrict__ offs, const int* __restrict__ csr,
    const bf16_t* __restrict__ ewsb,
    const void* __restrict__ gatb, const void* __restrict__ lng, const void* __restrict__ lnb,
    bf16_t* __restrict__ y, const int* __restrict__ flags, int N) {
    int bf = flags[0];
    const bf16_t* xb = bf ? (const bf16_t*)x_raw : xb_;
    int w = threadIdx.x >> 6, l = threadIdx.x & 63;
    int n = blockIdx.x * 4 + w;
    if (n >= N) return;
    int h = l >> 4;
    int col0 = l * 4;

    __shared__ int   srcs[4][64];
    __shared__ float ewt[4][4][68];

    int off = offs[n], deg = offs[n + 1] - off;

    float es = alsrc[n * 4 + h] + aldst[n * 4 + h];
    es = es > 0.f ? es : 0.2f * es;
    float wself = expf(fminf(es, 30.f));

    float a0 = 0.f, a1 = 0.f, a2 = 0.f, a3 = 0.f;
    f32x4 ssum = (f32x4){0.f, 0.f, 0.f, 0.f};

    for (int c0 = 0; c0 < deg; c0 += 64) {
        int cl = deg - c0; if (cl > 64) cl = 64;
        if (l < cl) {
            int sv = csr[off + c0 + l];
            srcs[w][l] = sv;
            bf16x4 wv4 = *(const bf16x4*)&ewsb[4 * (size_t)(off + c0 + l)];
            float w0 = (float)wv4[0], w1 = (float)wv4[1], w2 = (float)wv4[2], w3 = (float)wv4[3];
            ewt[w][0][l] = w0; ewt[w][1][l] = w1;
            ewt[w][2][l] = w2; ewt[w][3][l] = w3;
            ssum += (f32x4){w0, w1, w2, w3};
        }
        int i = 0;
        for (; i + 8 <= cl; i += 8) {
            int sv[8]; u32x2 vv[8];
#pragma unroll
            for (int k = 0; k < 8; k++) sv[k] = __builtin_amdgcn_readfirstlane(srcs[w][i + k]);
#pragma unroll
            for (int k = 0; k < 8; k++) vv[k] = ((const u32x2*)(hbuf + (size_t)sv[k] * 256))[l];
            f32x4 wqa = *(const f32x4*)&ewt[w][h][i];
            f32x4 wqb = *(const f32x4*)&ewt[w][h][i + 4];
#pragma unroll
            for (int k = 0; k < 4; k++) {
                a0 += wqa[k]*bflo(vv[k][0]); a1 += wqa[k]*bfhi(vv[k][0]);
                a2 += wqa[k]*bflo(vv[k][1]); a3 += wqa[k]*bfhi(vv[k][1]);
                a0 += wqb[k]*bflo(vv[k+4][0]); a1 += wqb[k]*bfhi(vv[k+4][0]);
                a2 += wqb[k]*bflo(vv[k+4][1]); a3 += wqb[k]*bfhi(vv[k+4][1]);
            }
        }
        for (; i + 4 <= cl; i += 4) {
            int s0 = __builtin_amdgcn_readfirstlane(srcs[w][i]);
            int s1 = __builtin_amdgcn_readfirstlane(srcs[w][i + 1]);
            int s2 = __builtin_amdgcn_readfirstlane(srcs[w][i + 2]);
            int s3 = __builtin_amdgcn_readfirstlane(srcs[w][i + 3]);
            u32x2 v0 = ((const u32x2*)(hbuf + (size_t)s0 * 256))[l];
            u32x2 v1 = ((const u32x2*)(hbuf + (size_t)s1 * 256))[l];
            u32x2 v2 = ((const u32x2*)(hbuf + (size_t)s2 * 256))[l];
            u32x2 v3 = ((const u32x2*)(hbuf + (size_t)s3 * 256))[l];
            f32x4 wq = *(const f32x4*)&ewt[w][h][i];
            a0 += wq[0]*bflo(v0[0]); a1 += wq[0]*bfhi(v0[0]); a2 += wq[0]*bflo(v0[1]); a3 += wq[0]*bfhi(v0[1]);
            a0 += wq[1]*bflo(v1[0]); a1 += wq[1]*bfhi(v1[0]); a2 += wq[1]*bflo(v1[1]); a3 += wq[1]*bfhi(v1[1]);
            a0 += wq[2]*bflo(v2[0]); a1 += wq[2]*bfhi(v2[0]); a2 += wq[2]*bflo(v2[1]); a3 += wq[2]*bfhi(v2[1]);
            a0 += wq[3]*bflo(v3[0]); a1 += wq[3]*bfhi(v3[0]); a2 += wq[3]*bflo(v3[1]); a3 += wq[3]*bfhi(v3[1]);
        }
        for (; i < cl; i++) {
            int sv = __builtin_amdgcn_readfirstlane(srcs[w][i]);
            float wgt = ewt[w][h][i];
            u32x2 v0 = ((const u32x2*)(hbuf + (size_t)sv * 256))[l];
            a0 += wgt*bflo(v0[0]); a1 += wgt*bfhi(v0[0]); a2 += wgt*bflo(v0[1]); a3 += wgt*bfhi(v0[1]);
        }
    }

#pragma unroll
    for (int d = 1; d < 64; d <<= 1) {
        ssum[0] += __shfl_xor(ssum[0], d);
        ssum[1] += __shfl_xor(ssum[1], d);
        ssum[2] += __shfl_xor(ssum[2], d);
        ssum[3] += __shfl_xor(ssum[3], d);
    }
    float dsum = (h == 0) ? ssum[0] : (h == 1) ? ssum[1] : (h == 2) ? ssum[2] : ssum[3];
    float di = 1.f / (dsum + wself);

    u32x2 sv2 = ((const u32x2*)(hbuf + (size_t)n * 256))[l];
    u32x2 xv  = ((const u32x2*)(xb   + (size_t)n * 256))[l];
    float v0f = (a0 + wself*bflo(sv2[0])) * di + loadf(gatb, col0 + 0, bf) + bflo(xv[0]);
    float v1f = (a1 + wself*bfhi(sv2[0])) * di + loadf(gatb, col0 + 1, bf) + bfhi(xv[0]);
    float v2f = (a2 + wself*bflo(sv2[1])) * di + loadf(gatb, col0 + 2, bf) + bflo(xv[1]);
    float v3f = (a3 + wself*bfhi(sv2[1])) * di + loadf(gatb, col0 + 3, bf) + bfhi(xv[1]);

    float s1 = v0f + v1f + v2f + v3f;
#pragma unroll
    for (int d = 1; d < 64; d <<= 1) s1 += __shfl_xor(s1, d);
    float mu = s1 * (1.f / 256.f);
    float c0f = v0f - mu, c1f = v1f - mu, c2f = v2f - mu, c3f = v3f - mu;
    float sq = c0f*c0f + c1f*c1f + c2f*c2f + c3f*c3f;
#pragma unroll
    for (int d = 1; d < 64; d <<= 1) sq += __shfl_xor(sq, d);
    float rs = rsqrtf(sq * (1.f / 256.f) + 1e-5f);

    bf16x4 o;
    o[0] = (bf16_t)(c0f * rs * loadf(lng, col0 + 0, bf) + loadf(lnb, col0 + 0, bf));
    o[1] = (bf16_t)(c1f * rs * loadf(lng, col0 + 1, bf) + loadf(lnb, col0 + 1, bf));
    o[2] = (bf16_t)(c2f * rs * loadf(lng, col0 + 2, bf) + loadf(lnb, col0 + 2, bf));
    o[3] = (bf16_t)(c3f * rs * loadf(lng, col0 + 3, bf) + loadf(lnb, col0 + 3, bf));
    *(bf16x4*)&y[(size_t)n * 256 + col0] = o;
}

// ---------------- final residual + LN2 (wave per row, vectorized) ----------------
__global__ __launch_bounds__(256) void ln_res(const bf16_t* __restrict__ f, const bf16_t* __restrict__ y,
                                              const void* __restrict__ g, const void* __restrict__ b,
                                              void* __restrict__ out, int N, const int* __restrict__ flags) {
    int bf = flags[0];
    int row = blockIdx.x * 4 + (threadIdx.x >> 6);
    int l = threadIdx.x & 63;
    if (row >= N) return;
    int col0 = l * 4;
    u32x2 fv = *(const u32x2*)(f + (size_t)row * 256 + col0);
    u32x2 yv = *(const u32x2*)(y + (size_t)row * 256 + col0);
    float v0 = bflo(fv[0]) + bflo(yv[0]);
    float v1 = bfhi(fv[0]) + bfhi(yv[0]);
    float v2 = bflo(fv[1]) + bflo(yv[1]);
    float v3 = bfhi(fv[1]) + bfhi(yv[1]);
    float s = v0 + v1 + v2 + v3;
#pragma unroll
    for (int d = 1; d < 64; d <<= 1) s += __shfl_xor(s, d);
    float mu = s * (1.f / 256.f);
    float c0 = v0 - mu, c1 = v1 - mu, c2 = v2 - mu, c3 = v3 - mu;
    float sq = c0*c0 + c1*c1 + c2*c2 + c3*c3;
#pragma unroll
    for (int d = 1; d < 64; d <<= 1) sq += __shfl_xor(sq, d);
    float rs = rsqrtf(sq * (1.f / 256.f) + 1e-5f);
    float o0 = c0 * rs * loadf(g, col0 + 0, bf) + loadf(b, col0 + 0, bf);
    float o1 = c1 * rs * loadf(g, col0 + 1, bf) + loadf(b, col0 + 1, bf);
    float o2 = c2 * rs * loadf(g, col0 + 2, bf) + loadf(b, col0 + 2, bf);
    float o3 = c3 * rs * loadf(g, col0 + 3, bf) + loadf(b, col0 + 3, bf);
    if (bf) {
        bf16x4 o; o[0]=(bf16_t)o0; o[1]=(bf16_t)o1; o[2]=(bf16_t)o2; o[3]=(bf16_t)o3;
        *(bf16x4*)&((bf16_t*)out)[(size_t)row * 256 + col0] = o;
    } else {
        f32x4 o = (f32x4){o0, o1, o2, o3};
        *(f32x4*)&((float*)out)[(size_t)row * 256 + col0] = o;
    }
}

extern "C" void kernel_launch(void* const* d_in, const int* in_sizes, int n_in,
                              void* d_out, int out_size, void* d_ws, size_t ws_size,
                              hipStream_t stream) {
    const void* x    = d_in[0];
    const void* ei   = d_in[1];
    const void* W    = d_in[2];
    const void* a_src= d_in[3];
    const void* a_dst= d_in[4];
    const void* gatb = d_in[5];
    const void* ln1g = d_in[6];
    const void* ln1b = d_in[7];
    const void* W1   = d_in[8];
    const void* b1   = d_in[9];
    const void* W2   = d_in[10];
    const void* b2   = d_in[11];
    const void* ln2g = d_in[12];
    const void* ln2b = d_in[13];

    const int DIM = 256, DFF = 512;
    int N = in_sizes[0] / DIM;   // 50000
    int E = in_sizes[1] / 2;     // 800000

    char* ws = (char*)d_ws;
    size_t o = 0;
    auto alloc = [&](size_t bytes) { void* p = ws + o; o += (bytes + 255) & ~(size_t)255; return p; };
    int*    flags  = (int*)alloc(256);
    bf16_t* WT     = (bf16_t*)alloc((size_t)DIM * DIM * 2);
    bf16_t* W1T    = (bf16_t*)alloc((size_t)DIM * DFF * 2);
    bf16_t* W2T    = (bf16_t*)alloc((size_t)DFF * DIM * 2);
    float*  alsrc  = (float*)alloc((size_t)N * 4 * 4);
    float*  aldst  = (float*)alloc((size_t)N * 4 * 4);
    int nch = (N + 255) / 256;
    int tot = nch * 256;
    int* deg      = (int*)alloc((size_t)tot * 4);
    int* offs     = (int*)alloc((size_t)(tot + 1) * 4);
    int* cursor   = (int*)alloc((size_t)tot * 4);
    int* chunkSum = (int*)alloc(256 * 4);
    int* chunkOff = (int*)alloc(256 * 4);
    int* csr      = (int*)alloc((size_t)E * 4);
    bf16_t* ewsb  = (bf16_t*)alloc((size_t)E * 8);
    bf16_t* h     = (bf16_t*)alloc((size_t)N * DIM * 2);
    bf16_t* yb    = (bf16_t*)alloc((size_t)N * DIM * 2);
    bf16_t* xb    = (bf16_t*)alloc((size_t)N * DIM * 2);
    bf16_t* fb    = h;   // h dead after gat_agg_ln; reuse for FFN output
    size_t remain = (ws_size > o) ? (ws_size - o) : 0;
    long CH = (long)(remain / ((size_t)DFF * 2));
    if (CH > N) CH = N;
    if (CH < 1024) CH = 1024;
    bf16_t* t1 = (bf16_t*)alloc((size_t)CH * DFF * 2);

    detect_k<<<1, 64, 0, stream>>>(x, ei, E, flags);
    hipMemsetAsync(deg, 0, (size_t)tot * 4, stream);

    tobf16_k<<<4096, 256, 0, stream>>>(x, xb, (long)N * DIM, flags);
    transpose3_k<<<1280, 256, 0, stream>>>(W, WT, W1, W1T, W2, W2T, flags);

    dim3 g1((N + 127) / 128, DIM / 128);
    gemm128<<<g1, 256, 0, stream>>>(xb, x, WT, nullptr, h, N, DIM, DIM, 0, flags,
                                    a_src, a_dst, alsrc, aldst, 1);

    deg_k<<<(E + 255) / 256, 256, 0, stream>>>(ei, deg, E, N, flags);
    scan1<<<nch, 256, 0, stream>>>(deg, offs, chunkSum);
    scan2<<<1, 256, 0, stream>>>(chunkSum, chunkOff, nch);
    scan3<<<(tot + 255) / 256, 256, 0, stream>>>(offs, chunkOff, cursor, tot);
    scatter_k<<<(E + 255) / 256, 256, 0, stream>>>(ei, cursor, csr, ewsb, alsrc, aldst, E, N, flags);

    gat_agg_ln<<<(N + 3) / 4, 256, 0, stream>>>(h, xb, x, alsrc, aldst, offs, csr, ewsb,
                                                gatb, ln1g, ln1b, yb, flags, N);

    for (long r0 = 0; r0 < N; r0 += CH) {
        int m = (int)((N - r0 < CH) ? (N - r0) : CH);
        dim3 g2((m + 127) / 128, DFF / 128);
        gemm128<<<g2, 256, 0, stream>>>(yb + r0 * DIM, nullptr, W1T, b1, t1, m, DFF, DIM, 1, flags,
                                        nullptr, nullptr, nullptr, nullptr, 0);
        dim3 g3((m + 127) / 128, DIM / 128);
        gemm128<<<g3, 256, 0, stream>>>(t1, nullptr, W2T, b2, fb + r0 * DIM, m, DIM, DFF, 0, flags,
                                        nullptr, nullptr, nullptr, nullptr, 0);
    }

    ln_res<<<(N + 3) / 4, 256, 0, stream>>>(fb, yb, ln2g, ln2b, d_out, N, flags);
}